// Round 6
// baseline (313.554 us; speedup 1.0000x reference)
//
#include <hip/hip_runtime.h>
#include <float.h>

typedef __bf16 bf16x8 __attribute__((ext_vector_type(8)));
typedef __bf16 bf16x4 __attribute__((ext_vector_type(4)));
typedef float  f32x4  __attribute__((ext_vector_type(4)));

#define G      256
#define MT     64      // points per tile
#define NW     8       // waves per block (512 threads)
#define H1DIM  64
#define H2DIM  128
#define LAT    256
#define H1PAD  72      // 144 B rows: 16B-aligned, 36 dw == 4 mod 32 -> 2-way (free) b128
#define H2PAD  136     // 272 B rows: 16B-aligned, 68 dw == 4 mod 32 -> 2-way (free) b128

// order-preserving float->uint map: max on uints == max on floats
__device__ __forceinline__ unsigned mapf(float f) {
  unsigned u = __float_as_uint(f);
  return (u & 0x80000000u) ? ~u : (u | 0x80000000u);
}
__device__ __forceinline__ float unmapf(unsigned u) {
  return (u & 0x80000000u) ? __uint_as_float(u & 0x7fffffffu) : __uint_as_float(~u);
}

// flush helper: vectors BY VALUE (no address-taken -> no scratch).
// Reduces over the 16 point-lanes, adds bias, atomicMax to global pooled[s].
// Wave w owns L3 feats [w*32, +32): feat = w*32 + mt*16 + q*4 + r.
__device__ __forceinline__ void flush2(f32x4 v0, f32x4 v1,
                                       int s, int w, int q, int nn,
                                       const float* __restrict__ b3,
                                       unsigned* __restrict__ pooled) {
  f32x4 vv[2] = {v0, v1};
  #pragma unroll
  for (int mt = 0; mt < 2; ++mt)
    #pragma unroll
    for (int r = 0; r < 4; ++r) {
      int feat = w * 32 + mt * 16 + q * 4 + r;
      float v = vv[mt][r] + b3[feat];
      v = fmaxf(v, __shfl_xor(v, 1));
      v = fmaxf(v, __shfl_xor(v, 2));
      v = fmaxf(v, __shfl_xor(v, 4));
      v = fmaxf(v, __shfl_xor(v, 8));
      if (nn == 0) atomicMax(&pooled[s * LAT + feat], mapf(v));
    }
}

// ---------------- fused centroid + MLP + segment max ----------------
// 512 thr = 8 waves, 64 points/tile. A-operand = weights (regs), B = activations (LDS).
// Feature split halves per-wave state vs 4-wave config: L1 wave w: feats [(w&3)*16,+16)
// x points [(w>>2)*32,+32); L2: feats [w*16,+16) x all 64 pts; L3: feats [w*32,+32).
// Persistent weights = 44 VGPR -> fits __launch_bounds__(512,4) 128-reg cap ->
// 2 blocks/CU, 16 waves/CU, two independent barrier groups.
__global__ __launch_bounds__(512, 4) void mlp_kernel(
    const float* __restrict__ pc,
    const float* __restrict__ W1, const float* __restrict__ b1,
    const float* __restrict__ W2, const float* __restrict__ b2,
    const float* __restrict__ W3, const float* __restrict__ b3,
    const int* __restrict__ sid,
    unsigned* __restrict__ pooled,
    float* __restrict__ sums,
    int n, int tiles_per_block) {
  __shared__ __align__(16) __bf16 shF[2][MT][8];
  __shared__ __align__(16) __bf16 sh1[MT][H1PAD];
  __shared__ __align__(16) __bf16 sh2[MT][H2PAD];
  __shared__ int segt[2][MT];

  const int t  = threadIdx.x;
  const int w  = t >> 6;         // wave id 0..7
  const int lane = t & 63;
  const int q  = lane >> 4;
  const int nn = lane & 15;
  const int fq = w & 3;          // L1 feature tile
  const int ph = w >> 2;         // L1 point half

  // ---- persistent weight fragments (A-operand: A[m=nn][k=q*8+j]) ----
  bf16x8 w1f;                    // L1, K=32 zero-padded (real K=4)
  #pragma unroll
  for (int j = 0; j < 8; ++j) {
    int k = q * 8 + j;
    w1f[j] = (k < 4) ? (__bf16)W1[k * H1DIM + fq * 16 + nn] : (__bf16)0.f;
  }
  float b1r[4];
  #pragma unroll
  for (int r = 0; r < 4; ++r) b1r[r] = b1[fq * 16 + q * 4 + r];

  bf16x8 w2f[2];                 // [ks]; wave owns L2 feats [w*16,+16)
  float  b2r[4];
  #pragma unroll
  for (int ks = 0; ks < 2; ++ks)
    #pragma unroll
    for (int j = 0; j < 8; ++j)
      w2f[ks][j] = (__bf16)W2[(ks * 32 + q * 8 + j) * H2DIM + w * 16 + nn];
  #pragma unroll
  for (int r = 0; r < 4; ++r) b2r[r] = b2[w * 16 + q * 4 + r];

  bf16x8 w3f[2][4];              // [mt][ks]; wave owns L3 feats [w*32,+32)
  #pragma unroll
  for (int mt = 0; mt < 2; ++mt) {
    int m = w * 32 + mt * 16 + nn;
    #pragma unroll
    for (int ks = 0; ks < 4; ++ks)
      #pragma unroll
      for (int j = 0; j < 8; ++j)
        w3f[mt][ks][j] = (__bf16)W3[(ks * 32 + q * 8 + j) * LAT + m];
  }

  const f32x4 zero4 = {0.f, 0.f, 0.f, 0.f};
  const bf16x8 zero8 = {};
  const f32x4 neginf4 = {-FLT_MAX, -FLT_MAX, -FLT_MAX, -FLT_MAX};

  f32x4 run[2];                  // running segment max (bias NOT included)
  run[0] = neginf4; run[1] = neginf4;

  // centroid accumulation state (staging threads t<64 only)
  float cx = 0.f, cy = 0.f, cz = 0.f, cc = 0.f;
  int   cseg = -1;

  const int tile0 = blockIdx.x * tiles_per_block;
  int first = tile0 * MT; if (first > n - 1) first = n - 1;
  int s_cur = sid[first];

  // ---- preload tile 0 into buffer 0 ----
  if (t < MT) {
    int p = tile0 * MT + t;
    bool valid = p < n;
    int pcl = valid ? p : (n - 1);
    const float* pp = pc + (size_t)pcl * 5;
    float fx = pp[4], p1 = pp[1], p2 = pp[2], p3 = pp[3];
    bf16x8 v = {};
    v[0] = (__bf16)fx; v[1] = (__bf16)p1; v[2] = (__bf16)p2; v[3] = (__bf16)p3;
    *reinterpret_cast<bf16x8*>(&shF[0][t][0]) = v;
    int s = sid[pcl];
    segt[0][t] = s;
    if (valid) { cseg = s; cx = p1; cy = p2; cz = p3; cc = 1.f; }
  }
  __syncthreads();

  int cur = 0;
  for (int ti = 0; ti < tiles_per_block; ++ti) {
    const int base = (tile0 + ti) * MT;
    if (base >= n) break;

    // ---- issue next tile's global loads NOW (latency hidden by tile compute) ----
    float pf1 = 0.f, pf2 = 0.f, pf3 = 0.f, pfx = 0.f;
    int   pfs = 0;
    bool  pfvalid = false;
    const int base2 = base + MT;
    const bool hasNext = (ti + 1 < tiles_per_block) && (base2 < n);
    if (hasNext && t < MT) {
      int p = base2 + t;
      pfvalid = p < n;
      int pcl = pfvalid ? p : (n - 1);
      const float* pp = pc + (size_t)pcl * 5;
      pfx = pp[4]; pf1 = pp[1]; pf2 = pp[2]; pf3 = pp[3];
      pfs = sid[pcl];
    }

    // ---- layer 1 (MFMA, K zero-padded): wave does feats fq*16..+16, points ph*32..+32
    #pragma unroll
    for (int nt = 0; nt < 2; ++nt) {
      int row = ph * 32 + nt * 16 + nn;
      bf16x8 ld = *reinterpret_cast<const bf16x8*>(&shF[cur][row][0]);
      bf16x8 af = (q == 0) ? ld : zero8;
      f32x4 acc1 = __builtin_amdgcn_mfma_f32_16x16x32_bf16(w1f, af, zero4, 0, 0, 0);
      bf16x4 pk;
      #pragma unroll
      for (int r = 0; r < 4; ++r)
        pk[r] = (__bf16)fmaxf(acc1[r] + b1r[r], 0.f);
      *reinterpret_cast<bf16x4*>(&sh1[row][fq * 16 + q * 4]) = pk;
    }
    __syncthreads();

    // ---- layer 2: (64x64) @ (64x128); wave owns 16 out-feats, nt serialized ----
    #pragma unroll
    for (int nt = 0; nt < 4; ++nt) {
      f32x4 acc2 = zero4;
      #pragma unroll
      for (int ks = 0; ks < 2; ++ks) {
        bf16x8 bfr = *reinterpret_cast<const bf16x8*>(&sh1[nt * 16 + nn][ks * 32 + q * 8]);
        acc2 = __builtin_amdgcn_mfma_f32_16x16x32_bf16(w2f[ks], bfr, acc2, 0, 0, 0);
      }
      bf16x4 pk;
      #pragma unroll
      for (int r = 0; r < 4; ++r)
        pk[r] = (__bf16)fmaxf(acc2[r] + b2r[r], 0.f);
      *reinterpret_cast<bf16x4*>(&sh2[nt * 16 + nn][w * 16 + q * 4]) = pk;
    }
    __syncthreads();

    // ---- layer 3: (64x128) @ (128x256); wave owns 32 out-feats ----
    f32x4 acc3[2][4];
    #pragma unroll
    for (int mt = 0; mt < 2; ++mt)
      #pragma unroll
      for (int nt = 0; nt < 4; ++nt) acc3[mt][nt] = zero4;
    #pragma unroll
    for (int ks = 0; ks < 4; ++ks) {
      #pragma unroll
      for (int nt = 0; nt < 4; ++nt) {
        bf16x8 bfr = *reinterpret_cast<const bf16x8*>(&sh2[nt * 16 + nn][ks * 32 + q * 8]);
        acc3[0][nt] = __builtin_amdgcn_mfma_f32_16x16x32_bf16(w3f[0][ks], bfr, acc3[0][nt], 0, 0, 0);
        acc3[1][nt] = __builtin_amdgcn_mfma_f32_16x16x32_bf16(w3f[1][ks], bfr, acc3[1][nt], 0, 0, 0);
      }
    }

    // ---- segment max (sorted ids; block-uniform control) ----
    int smin = segt[cur][0], smax = segt[cur][MT - 1];
    if (smin != s_cur) {           // previous segment ended exactly at tile edge
      flush2(run[0], run[1], s_cur, w, q, nn, b3, pooled);
      run[0] = neginf4; run[1] = neginf4;
      s_cur = smin;
    }
    if (smin == smax) {
      // fast path: whole tile in one segment -> fold into register running max
      #pragma unroll
      for (int mt = 0; mt < 2; ++mt)
        #pragma unroll
        for (int r = 0; r < 4; ++r) {
          float m01 = fmaxf(acc3[mt][0][r], acc3[mt][1][r]);
          float m23 = fmaxf(acc3[mt][2][r], acc3[mt][3][r]);
          run[mt][r] = fmaxf(run[mt][r], fmaxf(m01, m23));
        }
    } else {
      // slow path: tile crosses >=1 boundary (~255 occurrences total)
      int sg0 = segt[cur][nn],      sg1 = segt[cur][16 + nn];
      int sg2 = segt[cur][32 + nn], sg3 = segt[cur][48 + nn];
      for (int s = smin; s <= smax; ++s) {
        f32x4 tmp[2];
        #pragma unroll
        for (int mt = 0; mt < 2; ++mt)
          #pragma unroll
          for (int r = 0; r < 4; ++r) {
            float v0 = (sg0 == s) ? acc3[mt][0][r] : -FLT_MAX;
            float v1 = (sg1 == s) ? acc3[mt][1][r] : -FLT_MAX;
            float v2 = (sg2 == s) ? acc3[mt][2][r] : -FLT_MAX;
            float v3 = (sg3 == s) ? acc3[mt][3][r] : -FLT_MAX;
            tmp[mt][r] = fmaxf(fmaxf(v0, v1), fmaxf(v2, v3));
          }
        if (s < smax) {
          if (s == s_cur) {
            #pragma unroll
            for (int mt = 0; mt < 2; ++mt)
              #pragma unroll
              for (int r = 0; r < 4; ++r) run[mt][r] = fmaxf(run[mt][r], tmp[mt][r]);
            flush2(run[0], run[1], s, w, q, nn, b3, pooled);
            run[0] = neginf4; run[1] = neginf4;
          } else {
            flush2(tmp[0], tmp[1], s, w, q, nn, b3, pooled);
          }
        } else {
          #pragma unroll
          for (int mt = 0; mt < 2; ++mt)
            #pragma unroll
            for (int r = 0; r < 4; ++r) run[mt][r] = fmaxf(run[mt][r], tmp[mt][r]);
        }
      }
      s_cur = smax;
    }

    // ---- commit prefetched tile into the alternate buffer ----
    if (hasNext && t < MT) {
      bf16x8 v = {};
      v[0] = (__bf16)pfx; v[1] = (__bf16)pf1; v[2] = (__bf16)pf2; v[3] = (__bf16)pf3;
      *reinterpret_cast<bf16x8*>(&shF[cur ^ 1][t][0]) = v;
      segt[cur ^ 1][t] = pfs;
      if (pfvalid) {
        if (pfs != cseg) {
          if (cc > 0.f) {
            atomicAdd(&sums[cseg * 4 + 0], cx);
            atomicAdd(&sums[cseg * 4 + 1], cy);
            atomicAdd(&sums[cseg * 4 + 2], cz);
            atomicAdd(&sums[cseg * 4 + 3], cc);
          }
          cseg = pfs; cx = 0.f; cy = 0.f; cz = 0.f; cc = 0.f;
        }
        cx += pf1; cy += pf2; cz += pf3; cc += 1.f;
      }
    }
    __syncthreads();   // publishes shF[nxt]/segt[nxt]; protects sh1/sh2 reuse
    cur ^= 1;
  }
  flush2(run[0], run[1], s_cur, w, q, nn, b3, pooled);

  // final centroid flush
  if (t < MT && cc > 0.f) {
    atomicAdd(&sums[cseg * 4 + 0], cx);
    atomicAdd(&sums[cseg * 4 + 1], cy);
    atomicAdd(&sums[cseg * 4 + 2], cz);
    atomicAdd(&sums[cseg * 4 + 3], cc);
  }
}

// ---------------- head: pooled @ Wf + bf -> softplus, + centroid ----------------
__global__ void final_kernel(const float* __restrict__ sums, const unsigned* __restrict__ pooled,
                             const float* __restrict__ Wf, const float* __restrict__ bfv,
                             float* __restrict__ out) {
  __shared__ float red[4][3];
  int g = blockIdx.x;
  int t = threadIdx.x;   // 256 = LAT
  unsigned u = pooled[g * LAT + t];
  float f = u ? unmapf(u) : 0.f;
  float s0 = f * Wf[t * 3 + 0];
  float s1 = f * Wf[t * 3 + 1];
  float s2 = f * Wf[t * 3 + 2];
  #pragma unroll
  for (int off = 1; off < 64; off <<= 1) {
    s0 += __shfl_xor(s0, off);
    s1 += __shfl_xor(s1, off);
    s2 += __shfl_xor(s2, off);
  }
  int wave = t >> 6;
  if ((t & 63) == 0) { red[wave][0] = s0; red[wave][1] = s1; red[wave][2] = s2; }
  __syncthreads();
  if (t < 3) {
    float acc = bfv[t] + red[0][t] + red[1][t] + red[2][t] + red[3][t];
    float sp  = fmaxf(acc, 0.f) + log1pf(expf(-fabsf(acc)));
    float cnt = fmaxf(sums[g * 4 + 3], 1.f);
    float cen = sums[g * 4 + t] / cnt;
    out[g * 3 + t] = cen + sp;
  }
}

extern "C" void kernel_launch(void* const* d_in, const int* in_sizes, int n_in,
                              void* d_out, int out_size, void* d_ws, size_t ws_size,
                              hipStream_t stream) {
  const float* pc  = (const float*)d_in[0];
  const float* W1  = (const float*)d_in[1];
  const float* b1  = (const float*)d_in[2];
  const float* W2  = (const float*)d_in[3];
  const float* b2  = (const float*)d_in[4];
  const float* W3  = (const float*)d_in[5];
  const float* b3  = (const float*)d_in[6];
  const float* Wf  = (const float*)d_in[7];
  const float* bfv = (const float*)d_in[8];
  const int*   sid = (const int*)d_in[9];
  int n = in_sizes[0] / 5;

  float*    sums   = (float*)d_ws;                         // G*4 fp32
  unsigned* pooled = (unsigned*)((char*)d_ws + 4096);      // G*LAT mapped-uint maxes
  hipMemsetAsync(d_ws, 0, 4096 + (size_t)G * LAT * 4, stream);

  int tiles   = (n + MT - 1) / MT;
  int nblocks = 512;                         // 2 blocks/CU at __launch_bounds__(512,4)
  int tpb     = (tiles + nblocks - 1) / nblocks;
  mlp_kernel<<<nblocks, 512, 0, stream>>>(pc, W1, b1, W2, b2, W3, b3, sid, pooled, sums, n, tpb);

  final_kernel<<<G, 256, 0, stream>>>(sums, pooled, Wf, bfv, (float*)d_out);
}

// Round 7
// 300.367 us; speedup vs baseline: 1.0439x; 1.0439x over previous
//
#include <hip/hip_runtime.h>
#include <float.h>

typedef __bf16 bf16x8 __attribute__((ext_vector_type(8)));
typedef __bf16 bf16x4 __attribute__((ext_vector_type(4)));
typedef float  f32x4  __attribute__((ext_vector_type(4)));

#define G      256
#define MT     32      // points per tile (R4 config: only no-spill point found)
#define H1DIM  64
#define H2DIM  128
#define LAT    256
#define H1PAD  72      // 144 B rows: 16B-aligned, 36 dw == 4 mod 32 -> 2-way (free) b128
#define H2PAD  136     // 272 B rows: 16B-aligned, 68 dw == 4 mod 32 -> 2-way (free) b128

// order-preserving float->uint map: max on uints == max on floats
__device__ __forceinline__ unsigned mapf(float f) {
  unsigned u = __float_as_uint(f);
  return (u & 0x80000000u) ? ~u : (u | 0x80000000u);
}
__device__ __forceinline__ float unmapf(unsigned u) {
  return (u & 0x80000000u) ? __uint_as_float(u & 0x7fffffffu) : __uint_as_float(~u);
}

// flush helper: vectors BY VALUE (no address-taken -> no scratch).
// Reduces over the 16 point-lanes, adds bias, atomicMax to global pooled[s].
__device__ __forceinline__ void flush4(f32x4 v0, f32x4 v1, f32x4 v2, f32x4 v3,
                                       int s, int w, int q, int nn,
                                       const float* __restrict__ b3,
                                       unsigned* __restrict__ pooled) {
  f32x4 vv[4] = {v0, v1, v2, v3};
  #pragma unroll
  for (int mt = 0; mt < 4; ++mt)
    #pragma unroll
    for (int r = 0; r < 4; ++r) {
      int feat = w * 64 + mt * 16 + q * 4 + r;
      float v = vv[mt][r] + b3[feat];
      v = fmaxf(v, __shfl_xor(v, 1));
      v = fmaxf(v, __shfl_xor(v, 2));
      v = fmaxf(v, __shfl_xor(v, 4));
      v = fmaxf(v, __shfl_xor(v, 8));
      if (nn == 0) atomicMax(&pooled[s * LAT + feat], mapf(v));
    }
}

// ---------------- fused centroid + MLP + segment max ----------------
// R4 structure (MT=32, 4 waves, A=weights/B=activations, 176 regs no-spill) with
// ~15 regs of loop-carried state removed to fit the (256,3) 168-reg cap:
//   - b1 folded into W1 row k=4 (staged constant-1.0 input feature)
//   - b2 read from LDS per tile (broadcast ds_read_b128, short-lived)
//   - centroid running sums in per-lane LDS slots (stride 5 -> conflict-free)
__global__ __launch_bounds__(256, 3) void mlp_kernel(
    const float* __restrict__ pc,
    const float* __restrict__ W1, const float* __restrict__ b1,
    const float* __restrict__ W2, const float* __restrict__ b2,
    const float* __restrict__ W3, const float* __restrict__ b3,
    const int* __restrict__ sid,
    unsigned* __restrict__ pooled,
    float* __restrict__ sums,
    int n, int tiles_per_block) {
  __shared__ __align__(16) __bf16 shF[MT][8];
  __shared__ __align__(16) __bf16 sh1[MT][H1PAD];
  __shared__ __align__(16) __bf16 sh2[MT][H2PAD];
  __shared__ int   segt[MT];
  __shared__ __align__(16) float shB2[H2DIM];   // staged b2
  __shared__ float shC[MT][5];                  // centroid acc: x,y,z,count (pad->5)
  __shared__ int   shCseg[MT];

  const int t  = threadIdx.x;
  const int w  = t >> 6;         // wave id 0..3
  const int lane = t & 63;
  const int q  = lane >> 4;
  const int nn = lane & 15;

  // ---- persistent weight fragments (A-operand: A[m=nn][k=q*8+j]) ----
  bf16x8 w1f;                    // L1, K=32 zero-padded; k=4 row carries b1 (input 1.0)
  #pragma unroll
  for (int j = 0; j < 8; ++j) {
    int k = q * 8 + j;
    float wv = (k < 4) ? W1[k * H1DIM + w * 16 + nn]
             : (k == 4 ? b1[w * 16 + nn] : 0.f);
    w1f[j] = (__bf16)wv;
  }

  bf16x8 w2f[2][2];              // [mt][ks]
  #pragma unroll
  for (int mt = 0; mt < 2; ++mt) {
    int m = w * 32 + mt * 16 + nn;
    #pragma unroll
    for (int ks = 0; ks < 2; ++ks)
      #pragma unroll
      for (int j = 0; j < 8; ++j)
        w2f[mt][ks][j] = (__bf16)W2[(ks * 32 + q * 8 + j) * H2DIM + m];
  }

  bf16x8 w3f[4][4];              // [mt][ks]
  #pragma unroll
  for (int mt = 0; mt < 4; ++mt) {
    int m = w * 64 + mt * 16 + nn;
    #pragma unroll
    for (int ks = 0; ks < 4; ++ks)
      #pragma unroll
      for (int j = 0; j < 8; ++j)
        w3f[mt][ks][j] = (__bf16)W3[(ks * 32 + q * 8 + j) * LAT + m];
  }

  // stage b2 + init centroid slots (published by first tile's stage barrier)
  if (t < H2DIM) shB2[t] = b2[t];
  if (t < MT) { shCseg[t] = -1; shC[t][0] = 0.f; shC[t][1] = 0.f; shC[t][2] = 0.f; shC[t][3] = 0.f; }

  const f32x4 zero4 = {0.f, 0.f, 0.f, 0.f};
  const bf16x8 zero8 = {};
  const f32x4 neginf4 = {-FLT_MAX, -FLT_MAX, -FLT_MAX, -FLT_MAX};

  f32x4 run[4];                  // running segment max (bias NOT included)
  #pragma unroll
  for (int mt = 0; mt < 4; ++mt) run[mt] = neginf4;

  const int tile0 = blockIdx.x * tiles_per_block;
  int first = tile0 * MT; if (first > n - 1) first = n - 1;
  int s_cur = sid[first];

  for (int ti = 0; ti < tiles_per_block; ++ti) {
    const int base = (tile0 + ti) * MT;
    if (base >= n) break;

    // ---- stage 32 points (clamped duplicates are harmless for max) ----
    if (t < MT) {
      int p = base + t;
      bool valid = p < n;
      int pcl = valid ? p : (n - 1);
      const float* pp = pc + (size_t)pcl * 5;
      float fx = pp[4], p1 = pp[1], p2 = pp[2], p3 = pp[3];
      bf16x8 v = {};
      v[0] = (__bf16)fx;   // x first (concat order!)
      v[1] = (__bf16)p1;
      v[2] = (__bf16)p2;
      v[3] = (__bf16)p3;
      v[4] = (__bf16)1.0f; // bias slot: picks up b1 from W1 row k=4
      *reinterpret_cast<bf16x8*>(&shF[t][0]) = v;
      int s = sid[pcl];
      segt[t] = s;
      if (valid) {
        int pseg = shCseg[t];
        if (s != pseg) {
          float pcnt = shC[t][3];
          if (pcnt > 0.f) {
            atomicAdd(&sums[pseg * 4 + 0], shC[t][0]);
            atomicAdd(&sums[pseg * 4 + 1], shC[t][1]);
            atomicAdd(&sums[pseg * 4 + 2], shC[t][2]);
            atomicAdd(&sums[pseg * 4 + 3], pcnt);
          }
          shCseg[t] = s;
          shC[t][0] = p1; shC[t][1] = p2; shC[t][2] = p3; shC[t][3] = 1.f;
        } else {
          shC[t][0] += p1; shC[t][1] += p2; shC[t][2] += p3; shC[t][3] += 1.f;
        }
      }
    }
    __syncthreads();

    // ---- layer 1 (MFMA, K zero-padded; bias folded) ----
    {
      f32x4 acc1[2];
      #pragma unroll
      for (int nt = 0; nt < 2; ++nt) {
        bf16x8 ld = *reinterpret_cast<const bf16x8*>(&shF[nt * 16 + nn][0]);
        bf16x8 af = (q == 0) ? ld : zero8;
        acc1[nt] = __builtin_amdgcn_mfma_f32_16x16x32_bf16(w1f, af, zero4, 0, 0, 0);
      }
      #pragma unroll
      for (int nt = 0; nt < 2; ++nt) {
        bf16x4 pk;
        #pragma unroll
        for (int r = 0; r < 4; ++r)
          pk[r] = (__bf16)fmaxf(acc1[nt][r], 0.f);
        *reinterpret_cast<bf16x4*>(&sh1[nt * 16 + nn][w * 16 + q * 4]) = pk;
      }
    }
    __syncthreads();

    // ---- layer 2: (32x64) @ (64x128) ----
    {
      f32x4 acc2[2][2];
      #pragma unroll
      for (int mt = 0; mt < 2; ++mt)
        #pragma unroll
        for (int nt = 0; nt < 2; ++nt) acc2[mt][nt] = zero4;
      #pragma unroll
      for (int ks = 0; ks < 2; ++ks) {
        bf16x8 bfr[2];
        #pragma unroll
        for (int nt = 0; nt < 2; ++nt)
          bfr[nt] = *reinterpret_cast<const bf16x8*>(&sh1[nt * 16 + nn][ks * 32 + q * 8]);
        #pragma unroll
        for (int mt = 0; mt < 2; ++mt)
          #pragma unroll
          for (int nt = 0; nt < 2; ++nt)
            acc2[mt][nt] = __builtin_amdgcn_mfma_f32_16x16x32_bf16(w2f[mt][ks], bfr[nt], acc2[mt][nt], 0, 0, 0);
      }
      #pragma unroll
      for (int mt = 0; mt < 2; ++mt) {
        f32x4 b2v = *reinterpret_cast<const f32x4*>(&shB2[w * 32 + mt * 16 + q * 4]);
        #pragma unroll
        for (int nt = 0; nt < 2; ++nt) {
          bf16x4 pk;
          #pragma unroll
          for (int r = 0; r < 4; ++r)
            pk[r] = (__bf16)fmaxf(acc2[mt][nt][r] + b2v[r], 0.f);
          *reinterpret_cast<bf16x4*>(&sh2[nt * 16 + nn][w * 32 + mt * 16 + q * 4]) = pk;
        }
      }
    }
    __syncthreads();

    // ---- layer 3: (32x128) @ (128x256) ----
    f32x4 acc3[4][2];
    #pragma unroll
    for (int mt = 0; mt < 4; ++mt)
      #pragma unroll
      for (int nt = 0; nt < 2; ++nt) acc3[mt][nt] = zero4;
    #pragma unroll
    for (int ks = 0; ks < 4; ++ks) {
      bf16x8 bfr[2];
      #pragma unroll
      for (int nt = 0; nt < 2; ++nt)
        bfr[nt] = *reinterpret_cast<const bf16x8*>(&sh2[nt * 16 + nn][ks * 32 + q * 8]);
      #pragma unroll
      for (int mt = 0; mt < 4; ++mt)
        #pragma unroll
        for (int nt = 0; nt < 2; ++nt)
          acc3[mt][nt] = __builtin_amdgcn_mfma_f32_16x16x32_bf16(w3f[mt][ks], bfr[nt], acc3[mt][nt], 0, 0, 0);
    }

    // ---- segment max (sorted ids; block-uniform control) ----
    int smin = segt[0], smax = segt[MT - 1];
    if (smin != s_cur) {           // previous segment ended exactly at tile edge
      flush4(run[0], run[1], run[2], run[3], s_cur, w, q, nn, b3, pooled);
      #pragma unroll
      for (int mt = 0; mt < 4; ++mt) run[mt] = neginf4;
      s_cur = smin;
    }
    if (smin == smax) {
      // fast path: whole tile in one segment -> fold into register running max
      #pragma unroll
      for (int mt = 0; mt < 4; ++mt)
        #pragma unroll
        for (int r = 0; r < 4; ++r)
          run[mt][r] = fmaxf(run[mt][r], fmaxf(acc3[mt][0][r], acc3[mt][1][r]));
    } else {
      // slow path: tile crosses >=1 boundary (~255 occurrences total)
      int sg0 = segt[nn], sg1 = segt[16 + nn];
      for (int s = smin; s <= smax; ++s) {
        f32x4 tmp[4];
        #pragma unroll
        for (int mt = 0; mt < 4; ++mt)
          #pragma unroll
          for (int r = 0; r < 4; ++r) {
            float v0 = (sg0 == s) ? acc3[mt][0][r] : -FLT_MAX;
            float v1 = (sg1 == s) ? acc3[mt][1][r] : -FLT_MAX;
            tmp[mt][r] = fmaxf(v0, v1);
          }
        if (s < smax) {
          if (s == s_cur) {
            #pragma unroll
            for (int mt = 0; mt < 4; ++mt)
              #pragma unroll
              for (int r = 0; r < 4; ++r) run[mt][r] = fmaxf(run[mt][r], tmp[mt][r]);
            flush4(run[0], run[1], run[2], run[3], s, w, q, nn, b3, pooled);
            #pragma unroll
            for (int mt = 0; mt < 4; ++mt) run[mt] = neginf4;
          } else {
            flush4(tmp[0], tmp[1], tmp[2], tmp[3], s, w, q, nn, b3, pooled);
          }
        } else {
          #pragma unroll
          for (int mt = 0; mt < 4; ++mt)
            #pragma unroll
            for (int r = 0; r < 4; ++r) run[mt][r] = fmaxf(run[mt][r], tmp[mt][r]);
        }
      }
      s_cur = smax;
    }
    __syncthreads();   // protect shF/segt/sh1/sh2 against next iteration's writes
  }
  flush4(run[0], run[1], run[2], run[3], s_cur, w, q, nn, b3, pooled);

  // final centroid flush
  if (t < MT) {
    int pseg = shCseg[t];
    float pcnt = shC[t][3];
    if (pseg >= 0 && pcnt > 0.f) {
      atomicAdd(&sums[pseg * 4 + 0], shC[t][0]);
      atomicAdd(&sums[pseg * 4 + 1], shC[t][1]);
      atomicAdd(&sums[pseg * 4 + 2], shC[t][2]);
      atomicAdd(&sums[pseg * 4 + 3], pcnt);
    }
  }
}

// ---------------- head: pooled @ Wf + bf -> softplus, + centroid ----------------
__global__ void final_kernel(const float* __restrict__ sums, const unsigned* __restrict__ pooled,
                             const float* __restrict__ Wf, const float* __restrict__ bfv,
                             float* __restrict__ out) {
  __shared__ float red[4][3];
  int g = blockIdx.x;
  int t = threadIdx.x;   // 256 = LAT
  unsigned u = pooled[g * LAT + t];
  float f = u ? unmapf(u) : 0.f;
  float s0 = f * Wf[t * 3 + 0];
  float s1 = f * Wf[t * 3 + 1];
  float s2 = f * Wf[t * 3 + 2];
  #pragma unroll
  for (int off = 1; off < 64; off <<= 1) {
    s0 += __shfl_xor(s0, off);
    s1 += __shfl_xor(s1, off);
    s2 += __shfl_xor(s2, off);
  }
  int wave = t >> 6;
  if ((t & 63) == 0) { red[wave][0] = s0; red[wave][1] = s1; red[wave][2] = s2; }
  __syncthreads();
  if (t < 3) {
    float acc = bfv[t] + red[0][t] + red[1][t] + red[2][t] + red[3][t];
    float sp  = fmaxf(acc, 0.f) + log1pf(expf(-fabsf(acc)));
    float cnt = fmaxf(sums[g * 4 + 3], 1.f);
    float cen = sums[g * 4 + t] / cnt;
    out[g * 3 + t] = cen + sp;
  }
}

extern "C" void kernel_launch(void* const* d_in, const int* in_sizes, int n_in,
                              void* d_out, int out_size, void* d_ws, size_t ws_size,
                              hipStream_t stream) {
  const float* pc  = (const float*)d_in[0];
  const float* W1  = (const float*)d_in[1];
  const float* b1  = (const float*)d_in[2];
  const float* W2  = (const float*)d_in[3];
  const float* b2  = (const float*)d_in[4];
  const float* W3  = (const float*)d_in[5];
  const float* b3  = (const float*)d_in[6];
  const float* Wf  = (const float*)d_in[7];
  const float* bfv = (const float*)d_in[8];
  const int*   sid = (const int*)d_in[9];
  int n = in_sizes[0] / 5;

  float*    sums   = (float*)d_ws;                         // G*4 fp32
  unsigned* pooled = (unsigned*)((char*)d_ws + 4096);      // G*LAT mapped-uint maxes
  hipMemsetAsync(d_ws, 0, 4096 + (size_t)G * LAT * 4, stream);

  int tiles   = (n + MT - 1) / MT;
  int nblocks = 768;                         // 3 blocks/CU at __launch_bounds__(256,3)
  int tpb     = (tiles + nblocks - 1) / nblocks;
  mlp_kernel<<<nblocks, 256, 0, stream>>>(pc, W1, b1, W2, b2, W3, b3, sid, pooled, sums, n, tpb);

  final_kernel<<<G, 256, 0, stream>>>(sums, pooled, Wf, bfv, (float*)d_out);
}

// Round 8
// 252.301 us; speedup vs baseline: 1.2428x; 1.1905x over previous
//
#include <hip/hip_runtime.h>
#include <float.h>

typedef __bf16 bf16x8 __attribute__((ext_vector_type(8)));
typedef __bf16 bf16x4 __attribute__((ext_vector_type(4)));
typedef float  f32x4  __attribute__((ext_vector_type(4)));

#define G      256
#define MT     64      // points per tile (two 32-pt halves for L3/segmax)
#define H1DIM  64
#define H2DIM  128
#define LAT    256
#define H1PAD  72      // 144 B rows: 16B-aligned, 36 dw == 4 mod 32 -> 2-way (free) b128
#define H2PAD  136     // 272 B rows: 16B-aligned, 68 dw == 4 mod 32 -> 2-way (free) b128

// order-preserving float->uint map: max on uints == max on floats
__device__ __forceinline__ unsigned mapf(float f) {
  unsigned u = __float_as_uint(f);
  return (u & 0x80000000u) ? ~u : (u | 0x80000000u);
}
__device__ __forceinline__ float unmapf(unsigned u) {
  return (u & 0x80000000u) ? __uint_as_float(u & 0x7fffffffu) : __uint_as_float(~u);
}

// flush helper: vectors BY VALUE (no address-taken -> no scratch).
// Reduces over the 16 point-lanes, adds bias, atomicMax to global pooled[s].
__device__ __forceinline__ void flush4(f32x4 v0, f32x4 v1, f32x4 v2, f32x4 v3,
                                       int s, int w, int q, int nn,
                                       const float* __restrict__ b3,
                                       unsigned* __restrict__ pooled) {
  f32x4 vv[4] = {v0, v1, v2, v3};
  #pragma unroll
  for (int mt = 0; mt < 4; ++mt)
    #pragma unroll
    for (int r = 0; r < 4; ++r) {
      int feat = w * 64 + mt * 16 + q * 4 + r;
      float v = vv[mt][r] + b3[feat];
      v = fmaxf(v, __shfl_xor(v, 1));
      v = fmaxf(v, __shfl_xor(v, 2));
      v = fmaxf(v, __shfl_xor(v, 4));
      v = fmaxf(v, __shfl_xor(v, 8));
      if (nn == 0) atomicMax(&pooled[s * LAT + feat], mapf(v));
    }
}

// ---------------- fused centroid + MLP + segment max ----------------
// R4 register recipe (4 waves, (256,2), no cap squeeze -> no spill) + MT=64:
//  - L1 serialized per 16-pt group; L2 in two nt-pair passes (16 acc regs live)
//  - L3 + segmax as two independent 32-pt halves (acc3[4][2]=32 regs live, = R4)
//  - double-buffered shF/segt: prefetch at top, commit before end barrier
//    -> 3 barriers per 64 points (R4: 4 per 32)
//  - b1 folded into W1 k=4 row (constant-1.0 input); b2 in LDS; centroids in LDS
__global__ __launch_bounds__(256, 2) void mlp_kernel(
    const float* __restrict__ pc,
    const float* __restrict__ W1, const float* __restrict__ b1,
    const float* __restrict__ W2, const float* __restrict__ b2,
    const float* __restrict__ W3, const float* __restrict__ b3,
    const int* __restrict__ sid,
    unsigned* __restrict__ pooled,
    float* __restrict__ sums,
    int n, int tiles_per_block) {
  __shared__ __align__(16) __bf16 shF[2][MT][8];
  __shared__ __align__(16) __bf16 sh1[MT][H1PAD];
  __shared__ __align__(16) __bf16 sh2[MT][H2PAD];
  __shared__ int   segt[2][MT];
  __shared__ __align__(16) float shB2[H2DIM];   // staged b2
  __shared__ float shC[MT][5];                  // centroid acc: x,y,z,count (stride 5)
  __shared__ int   shCseg[MT];

  const int t  = threadIdx.x;
  const int w  = t >> 6;         // wave id 0..3
  const int lane = t & 63;
  const int q  = lane >> 4;
  const int nn = lane & 15;

  // ---- persistent weight fragments (A-operand: A[m=nn][k=q*8+j]) ----
  bf16x8 w1f;                    // L1, K=32 zero-padded; k=4 row carries b1
  #pragma unroll
  for (int j = 0; j < 8; ++j) {
    int k = q * 8 + j;
    float wv = (k < 4) ? W1[k * H1DIM + w * 16 + nn]
             : (k == 4 ? b1[w * 16 + nn] : 0.f);
    w1f[j] = (__bf16)wv;
  }

  bf16x8 w2f[2][2];              // [mt][ks]
  #pragma unroll
  for (int mt = 0; mt < 2; ++mt) {
    int m = w * 32 + mt * 16 + nn;
    #pragma unroll
    for (int ks = 0; ks < 2; ++ks)
      #pragma unroll
      for (int j = 0; j < 8; ++j)
        w2f[mt][ks][j] = (__bf16)W2[(ks * 32 + q * 8 + j) * H2DIM + m];
  }

  bf16x8 w3f[4][4];              // [mt][ks]
  #pragma unroll
  for (int mt = 0; mt < 4; ++mt) {
    int m = w * 64 + mt * 16 + nn;
    #pragma unroll
    for (int ks = 0; ks < 4; ++ks)
      #pragma unroll
      for (int j = 0; j < 8; ++j)
        w3f[mt][ks][j] = (__bf16)W3[(ks * 32 + q * 8 + j) * LAT + m];
  }

  if (t < H2DIM) shB2[t] = b2[t];
  if (t < MT) { shCseg[t] = -1; shC[t][0] = 0.f; shC[t][1] = 0.f; shC[t][2] = 0.f; shC[t][3] = 0.f; }

  const f32x4 zero4 = {0.f, 0.f, 0.f, 0.f};
  const bf16x8 zero8 = {};
  const f32x4 neginf4 = {-FLT_MAX, -FLT_MAX, -FLT_MAX, -FLT_MAX};

  f32x4 run[4];                  // running segment max (bias NOT included)
  #pragma unroll
  for (int mt = 0; mt < 4; ++mt) run[mt] = neginf4;

  const int tile0 = blockIdx.x * tiles_per_block;
  int first = tile0 * MT; if (first > n - 1) first = n - 1;
  int s_cur = sid[first];

  // ---- preload tile 0 into buffer 0 (includes centroid fold) ----
  if (t < MT) {
    int p = tile0 * MT + t;
    bool valid = p < n;
    int pcl = valid ? p : (n - 1);
    const float* pp = pc + (size_t)pcl * 5;
    float fx = pp[4], p1 = pp[1], p2 = pp[2], p3 = pp[3];
    bf16x8 v = {};
    v[0] = (__bf16)fx; v[1] = (__bf16)p1; v[2] = (__bf16)p2; v[3] = (__bf16)p3;
    v[4] = (__bf16)1.0f;  // bias slot
    *reinterpret_cast<bf16x8*>(&shF[0][t][0]) = v;
    int s = sid[pcl];
    segt[0][t] = s;
    if (valid) { shCseg[t] = s; shC[t][0] = p1; shC[t][1] = p2; shC[t][2] = p3; shC[t][3] = 1.f; }
  }
  __syncthreads();

  int cur = 0;
  for (int ti = 0; ti < tiles_per_block; ++ti) {
    const int base = (tile0 + ti) * MT;
    if (base >= n) break;

    // ---- issue next tile's global loads NOW (hidden behind this tile's compute) ----
    float pf1 = 0.f, pf2 = 0.f, pf3 = 0.f, pfx = 0.f;
    int   pfs = 0;
    bool  pfvalid = false;
    const int base2 = base + MT;
    const bool hasNext = (ti + 1 < tiles_per_block) && (base2 < n);
    if (hasNext && t < MT) {
      int p = base2 + t;
      pfvalid = p < n;
      int pcl = pfvalid ? p : (n - 1);
      const float* pp = pc + (size_t)pcl * 5;
      pfx = pp[4]; pf1 = pp[1]; pf2 = pp[2]; pf3 = pp[3];
      pfs = sid[pcl];
    }

    // ---- layer 1 (MFMA, K zero-padded; bias folded), serialized per 16 pts ----
    #pragma unroll
    for (int nt = 0; nt < 4; ++nt) {
      int row = nt * 16 + nn;
      bf16x8 ld = *reinterpret_cast<const bf16x8*>(&shF[cur][row][0]);
      bf16x8 af = (q == 0) ? ld : zero8;
      f32x4 acc1 = __builtin_amdgcn_mfma_f32_16x16x32_bf16(w1f, af, zero4, 0, 0, 0);
      bf16x4 pk;
      #pragma unroll
      for (int r = 0; r < 4; ++r)
        pk[r] = (__bf16)fmaxf(acc1[r], 0.f);
      *reinterpret_cast<bf16x4*>(&sh1[row][w * 16 + q * 4]) = pk;
    }
    __syncthreads();

    // ---- layer 2: (64x64) @ (64x128), two nt-pair passes (16 acc regs live) ----
    #pragma unroll
    for (int np = 0; np < 2; ++np) {
      f32x4 acc2[2][2];
      #pragma unroll
      for (int mt = 0; mt < 2; ++mt)
        #pragma unroll
        for (int nt = 0; nt < 2; ++nt) acc2[mt][nt] = zero4;
      #pragma unroll
      for (int ks = 0; ks < 2; ++ks) {
        bf16x8 bfr[2];
        #pragma unroll
        for (int nt = 0; nt < 2; ++nt)
          bfr[nt] = *reinterpret_cast<const bf16x8*>(&sh1[(np * 2 + nt) * 16 + nn][ks * 32 + q * 8]);
        #pragma unroll
        for (int mt = 0; mt < 2; ++mt)
          #pragma unroll
          for (int nt = 0; nt < 2; ++nt)
            acc2[mt][nt] = __builtin_amdgcn_mfma_f32_16x16x32_bf16(w2f[mt][ks], bfr[nt], acc2[mt][nt], 0, 0, 0);
      }
      #pragma unroll
      for (int mt = 0; mt < 2; ++mt) {
        f32x4 b2v = *reinterpret_cast<const f32x4*>(&shB2[w * 32 + mt * 16 + q * 4]);
        #pragma unroll
        for (int nt = 0; nt < 2; ++nt) {
          bf16x4 pk;
          #pragma unroll
          for (int r = 0; r < 4; ++r)
            pk[r] = (__bf16)fmaxf(acc2[mt][nt][r] + b2v[r], 0.f);
          *reinterpret_cast<bf16x4*>(&sh2[(np * 2 + nt) * 16 + nn][w * 32 + mt * 16 + q * 4]) = pk;
        }
      }
    }
    __syncthreads();

    // ---- layer 3 + segment max: two independent 32-pt halves ----
    #pragma unroll
    for (int h = 0; h < 2; ++h) {
      f32x4 acc3[4][2];
      #pragma unroll
      for (int mt = 0; mt < 4; ++mt)
        #pragma unroll
        for (int nt = 0; nt < 2; ++nt) acc3[mt][nt] = zero4;
      #pragma unroll
      for (int ks = 0; ks < 4; ++ks) {
        bf16x8 bfr[2];
        #pragma unroll
        for (int nt = 0; nt < 2; ++nt)
          bfr[nt] = *reinterpret_cast<const bf16x8*>(&sh2[h * 32 + nt * 16 + nn][ks * 32 + q * 8]);
        #pragma unroll
        for (int mt = 0; mt < 4; ++mt)
          #pragma unroll
          for (int nt = 0; nt < 2; ++nt)
            acc3[mt][nt] = __builtin_amdgcn_mfma_f32_16x16x32_bf16(w3f[mt][ks], bfr[nt], acc3[mt][nt], 0, 0, 0);
      }

      int smin = segt[cur][h * 32], smax = segt[cur][h * 32 + 31];
      if (smin != s_cur) {         // previous segment ended exactly at half edge
        flush4(run[0], run[1], run[2], run[3], s_cur, w, q, nn, b3, pooled);
        #pragma unroll
        for (int mt = 0; mt < 4; ++mt) run[mt] = neginf4;
        s_cur = smin;
      }
      if (smin == smax) {
        // fast path: whole half in one segment
        #pragma unroll
        for (int mt = 0; mt < 4; ++mt)
          #pragma unroll
          for (int r = 0; r < 4; ++r)
            run[mt][r] = fmaxf(run[mt][r], fmaxf(acc3[mt][0][r], acc3[mt][1][r]));
      } else {
        // slow path: half crosses >=1 boundary (rare)
        int sg0 = segt[cur][h * 32 + nn], sg1 = segt[cur][h * 32 + 16 + nn];
        for (int s = smin; s <= smax; ++s) {
          f32x4 tmp[4];
          #pragma unroll
          for (int mt = 0; mt < 4; ++mt)
            #pragma unroll
            for (int r = 0; r < 4; ++r) {
              float v0 = (sg0 == s) ? acc3[mt][0][r] : -FLT_MAX;
              float v1 = (sg1 == s) ? acc3[mt][1][r] : -FLT_MAX;
              tmp[mt][r] = fmaxf(v0, v1);
            }
          if (s < smax) {
            if (s == s_cur) {
              #pragma unroll
              for (int mt = 0; mt < 4; ++mt)
                #pragma unroll
                for (int r = 0; r < 4; ++r) run[mt][r] = fmaxf(run[mt][r], tmp[mt][r]);
              flush4(run[0], run[1], run[2], run[3], s, w, q, nn, b3, pooled);
              #pragma unroll
              for (int mt = 0; mt < 4; ++mt) run[mt] = neginf4;
            } else {
              flush4(tmp[0], tmp[1], tmp[2], tmp[3], s, w, q, nn, b3, pooled);
            }
          } else {
            #pragma unroll
            for (int mt = 0; mt < 4; ++mt)
              #pragma unroll
              for (int r = 0; r < 4; ++r) run[mt][r] = fmaxf(run[mt][r], tmp[mt][r]);
          }
        }
        s_cur = smax;
      }
    }

    // ---- commit prefetched tile into the alternate buffer (+ centroid fold) ----
    if (hasNext && t < MT) {
      bf16x8 v = {};
      v[0] = (__bf16)pfx; v[1] = (__bf16)pf1; v[2] = (__bf16)pf2; v[3] = (__bf16)pf3;
      v[4] = (__bf16)1.0f;
      *reinterpret_cast<bf16x8*>(&shF[cur ^ 1][t][0]) = v;
      segt[cur ^ 1][t] = pfs;
      if (pfvalid) {
        int pseg = shCseg[t];
        if (pfs != pseg) {
          float pcnt = shC[t][3];
          if (pcnt > 0.f) {
            atomicAdd(&sums[pseg * 4 + 0], shC[t][0]);
            atomicAdd(&sums[pseg * 4 + 1], shC[t][1]);
            atomicAdd(&sums[pseg * 4 + 2], shC[t][2]);
            atomicAdd(&sums[pseg * 4 + 3], pcnt);
          }
          shCseg[t] = pfs;
          shC[t][0] = pf1; shC[t][1] = pf2; shC[t][2] = pf3; shC[t][3] = 1.f;
        } else {
          shC[t][0] += pf1; shC[t][1] += pf2; shC[t][2] += pf3; shC[t][3] += 1.f;
        }
      }
    }
    __syncthreads();   // publishes shF[nxt]/segt[nxt]; protects sh1/sh2 reuse
    cur ^= 1;
  }
  flush4(run[0], run[1], run[2], run[3], s_cur, w, q, nn, b3, pooled);

  // final centroid flush
  if (t < MT) {
    int pseg = shCseg[t];
    float pcnt = shC[t][3];
    if (pseg >= 0 && pcnt > 0.f) {
      atomicAdd(&sums[pseg * 4 + 0], shC[t][0]);
      atomicAdd(&sums[pseg * 4 + 1], shC[t][1]);
      atomicAdd(&sums[pseg * 4 + 2], shC[t][2]);
      atomicAdd(&sums[pseg * 4 + 3], pcnt);
    }
  }
}

// ---------------- head: pooled @ Wf + bf -> softplus, + centroid ----------------
__global__ void final_kernel(const float* __restrict__ sums, const unsigned* __restrict__ pooled,
                             const float* __restrict__ Wf, const float* __restrict__ bfv,
                             float* __restrict__ out) {
  __shared__ float red[4][3];
  int g = blockIdx.x;
  int t = threadIdx.x;   // 256 = LAT
  unsigned u = pooled[g * LAT + t];
  float f = u ? unmapf(u) : 0.f;
  float s0 = f * Wf[t * 3 + 0];
  float s1 = f * Wf[t * 3 + 1];
  float s2 = f * Wf[t * 3 + 2];
  #pragma unroll
  for (int off = 1; off < 64; off <<= 1) {
    s0 += __shfl_xor(s0, off);
    s1 += __shfl_xor(s1, off);
    s2 += __shfl_xor(s2, off);
  }
  int wave = t >> 6;
  if ((t & 63) == 0) { red[wave][0] = s0; red[wave][1] = s1; red[wave][2] = s2; }
  __syncthreads();
  if (t < 3) {
    float acc = bfv[t] + red[0][t] + red[1][t] + red[2][t] + red[3][t];
    float sp  = fmaxf(acc, 0.f) + log1pf(expf(-fabsf(acc)));
    float cnt = fmaxf(sums[g * 4 + 3], 1.f);
    float cen = sums[g * 4 + t] / cnt;
    out[g * 3 + t] = cen + sp;
  }
}

extern "C" void kernel_launch(void* const* d_in, const int* in_sizes, int n_in,
                              void* d_out, int out_size, void* d_ws, size_t ws_size,
                              hipStream_t stream) {
  const float* pc  = (const float*)d_in[0];
  const float* W1  = (const float*)d_in[1];
  const float* b1  = (const float*)d_in[2];
  const float* W2  = (const float*)d_in[3];
  const float* b2  = (const float*)d_in[4];
  const float* W3  = (const float*)d_in[5];
  const float* b3  = (const float*)d_in[6];
  const float* Wf  = (const float*)d_in[7];
  const float* bfv = (const float*)d_in[8];
  const int*   sid = (const int*)d_in[9];
  int n = in_sizes[0] / 5;

  float*    sums   = (float*)d_ws;                         // G*4 fp32
  unsigned* pooled = (unsigned*)((char*)d_ws + 4096);      // G*LAT mapped-uint maxes
  hipMemsetAsync(d_ws, 0, 4096 + (size_t)G * LAT * 4, stream);

  int tiles   = (n + MT - 1) / MT;
  int nblocks = 512;                         // 2 blocks/CU at __launch_bounds__(256,2)
  int tpb     = (tiles + nblocks - 1) / nblocks;
  mlp_kernel<<<nblocks, 256, 0, stream>>>(pc, W1, b1, W2, b2, W3, b3, sid, pooled, sums, n, tpb);

  final_kernel<<<G, 256, 0, stream>>>(sums, pooled, Wf, bfv, (float*)d_out);
}